// Round 2
// baseline (312.029 us; speedup 1.0000x reference)
//
#include <hip/hip_runtime.h>
#include <hip/hip_cooperative_groups.h>
#include <math.h>

namespace cg = cooperative_groups;

#define NROWS 8192
#define NCOLS 4096
#define NB 256
#define RPB 32            // rows per block
#define EPS 1e-8f

// Scratch in device globals: graph-capture safe, no ws_size dependence.
__device__ float g_partials[NB * NCOLS];  // 4 MB per-block column partials
__device__ float g_S[NCOLS];              // masked column sums
__device__ float g_n0[NB];                // per-block label-0 counts
__device__ float g_msq[NB];               // per-block ||S||^2 partials (16 cols each)
__device__ float g_A[NB];                 // per-block sum of mask0 * |dot|/xnorm
__device__ float g_B[NB];                 // per-block sum of mask1 * |dot|/xnorm

__global__ __launch_bounds__(1024, 4) void fused(const float* __restrict__ labels,
                                                 const float* __restrict__ datas,
                                                 float* __restrict__ out) {
    cg::grid_group grid = cg::this_grid();
    const int b = blockIdx.x, t = threadIdx.x;
    const int r0 = b * RPB;
    const float4* d4 = (const float4*)datas;

    __shared__ float sh_mask[RPB];
    __shared__ float sh2[64][17];   // phase-2 transpose buffer (padded)
    __shared__ float sh_red[32];

    // ---- phase 0: masks for this block's 32 rows + count ----
    if (t < RPB) {
        float l0 = labels[2 * (r0 + t)];
        float l1 = labels[2 * (r0 + t) + 1];
        sh_mask[t] = (l0 >= l1) ? 1.f : 0.f;   // argmax ties -> index 0
    }
    __syncthreads();
    if (t == 0) {
        float c = 0.f;
        #pragma unroll
        for (int r = 0; r < RPB; ++r) c += sh_mask[r];
        g_n0[b] = c;
    }

    // ---- phase 1: masked column partial sums (skip unmasked rows) ----
    float4 acc = {0.f, 0.f, 0.f, 0.f};
    for (int r = 0; r < RPB; ++r) {
        if (sh_mask[r] != 0.f) {               // block-uniform branch
            float4 v = d4[(size_t)(r0 + r) * (NCOLS / 4) + t];
            acc.x += v.x; acc.y += v.y; acc.z += v.z; acc.w += v.w;
        }
    }
    ((float4*)g_partials)[(size_t)b * (NCOLS / 4) + t] = acc;

    grid.sync();

    // ---- phase 2: reduce partials -> S; block b owns cols [b*16, b*16+16) ----
    {
        int col = t & 15, row = t >> 4;        // row 0..63 (partial-row group)
        int c0 = b * 16;
        float s = 0.f;
        #pragma unroll
        for (int j = 0; j < 4; ++j)
            s += g_partials[(size_t)(row + 64 * j) * NCOLS + c0 + col];
        sh2[row][col] = s;
    }
    __syncthreads();
    if (t < 16) {
        float tot = 0.f;
        #pragma unroll
        for (int r = 0; r < 64; ++r) tot += sh2[r][t];
        g_S[b * 16 + t] = tot;
        sh_red[t] = tot * tot;
    }
    __syncthreads();
    if (t == 0) {
        float m = 0.f;
        #pragma unroll
        for (int i = 0; i < 16; ++i) m += sh_red[i];
        g_msq[b] = m;
    }

    grid.sync();

    // ---- phase 3: per-row |dot|/xnorm; accumulate A (mask0) / B (mask1) ----
    {
        int lane = t & 63, w = t >> 6;         // 16 waves, 2 rows each
        const float4* s4 = (const float4*)g_S;
        float pa = 0.f, pb = 0.f;
        #pragma unroll
        for (int rr = 0; rr < 2; ++rr) {
            int rloc = w * 2 + rr;
            size_t base = (size_t)(r0 + rloc) * (NCOLS / 4);
            float dot = 0.f, sq = 0.f;
            #pragma unroll 4
            for (int k = 0; k < 16; ++k) {
                float4 v  = d4[base + lane + (k << 6)];
                float4 sv = s4[lane + (k << 6)];
                dot += v.x * sv.x + v.y * sv.y + v.z * sv.z + v.w * sv.w;
                sq  += v.x * v.x + v.y * v.y + v.z * v.z + v.w * v.w;
            }
            #pragma unroll
            for (int off = 32; off; off >>= 1) {
                dot += __shfl_xor(dot, off);
                sq  += __shfl_xor(sq, off);
            }
            float a = fabsf(dot) / fmaxf(sqrtf(sq), EPS);
            float m = sh_mask[rloc];
            pa += m * a;
            pb += (1.f - m) * a;
        }
        if (lane == 0) { sh_red[w] = pa; sh_red[w + 16] = pb; }
    }
    __syncthreads();
    if (t == 0) {
        float A = 0.f, B = 0.f;
        #pragma unroll
        for (int i = 0; i < 16; ++i) { A += sh_red[i]; B += sh_red[i + 16]; }
        g_A[b] = A; g_B[b] = B;
    }

    grid.sync();

    // ---- phase 4: block 0 reduces per-block partials, writes 3 outputs ----
    if (b == 0 && t < 64) {
        float n0 = 0.f, msq = 0.f, A = 0.f, B = 0.f;
        #pragma unroll
        for (int j = 0; j < 4; ++j) {
            int i = t + j * 64;
            n0 += g_n0[i]; msq += g_msq[i]; A += g_A[i]; B += g_B[i];
        }
        #pragma unroll
        for (int off = 32; off; off >>= 1) {
            n0  += __shfl_xor(n0, off);
            msq += __shfl_xor(msq, off);
            A   += __shfl_xor(A, off);
            B   += __shfl_xor(B, off);
        }
        if (t == 0) {
            float n1 = (float)NROWS - n0;
            float n0d = fmaxf(n0, 1.f), n1d = fmaxf(n1, 1.f);
            // n0d * max(||S||/n0d, eps) == max(||S||, n0d*eps)
            float D = fmaxf(sqrtf(msq), n0d * EPS);
            float simL = (n0 > 0.f) ? (n0 - A / D) / n0d : 0.f;
            float difL = (n0 > 0.f && n1 > 0.f) ? (B / D) / n1d : 0.f;
            out[0] = simL + difL;
            out[1] = simL;
            out[2] = difL;
        }
    }
}

extern "C" void kernel_launch(void* const* d_in, const int* in_sizes, int n_in,
                              void* d_out, int out_size, void* d_ws, size_t ws_size,
                              hipStream_t stream) {
    const float* labels = (const float*)d_in[0];
    const float* datas  = (const float*)d_in[1];
    float* out = (float*)d_out;
    void* args[] = {(void*)&labels, (void*)&datas, (void*)&out};
    hipLaunchCooperativeKernel((const void*)fused, dim3(NB), dim3(1024),
                               args, 0, stream);
}

// Round 3
// 208.662 us; speedup vs baseline: 1.4954x; 1.4954x over previous
//
#include <hip/hip_runtime.h>
#include <math.h>

#define NROWS 8192
#define NCOLS 4096
#define NC4 1024          // NCOLS/4
#define EPS 1e-8f

// Scratch in device globals: graph-capture safe, re-written every call.
__device__ float g_partials[256 * NCOLS];  // 4 MB per-block column partials
__device__ float g_S[NCOLS];               // masked column sums
__device__ float g_n0[256];                // per-block label-0 counts
__device__ float g_msq[64];                // per-block ||S||^2 partials
__device__ float g_A[2048];                // per-block sum mask0 * |dot|/xnorm
__device__ float g_B[2048];                // per-block sum mask1 * |dot|/xnorm

// ---- K1: masked column partial sums (256 blocks x 1024), skips label-1 rows ----
__global__ __launch_bounds__(1024) void k_colsum(const float* __restrict__ labels,
                                                 const float* __restrict__ datas) {
    const int b = blockIdx.x, t = threadIdx.x;
    const int r0 = b * 32;
    __shared__ float shm[32];
    if (t < 32) {
        float l0 = labels[2 * (r0 + t)];
        float l1 = labels[2 * (r0 + t) + 1];
        shm[t] = (l0 >= l1) ? 1.f : 0.f;   // argmax ties -> index 0
    }
    __syncthreads();
    if (t == 0) {
        float c = 0.f;
        #pragma unroll
        for (int r = 0; r < 32; ++r) c += shm[r];
        g_n0[b] = c;
    }
    const float4* d4 = (const float4*)datas;
    float4 acc = {0.f, 0.f, 0.f, 0.f};
    for (int r = 0; r < 32; ++r) {
        if (shm[r] != 0.f) {               // wave-uniform branch
            float4 v = d4[(size_t)(r0 + r) * NC4 + t];
            acc.x += v.x; acc.y += v.y; acc.z += v.z; acc.w += v.w;
        }
    }
    ((float4*)g_partials)[(size_t)b * NC4 + t] = acc;
}

// ---- K2: reduce partials -> S, ||S||^2 partials (64 blocks x 1024) ----
__global__ __launch_bounds__(1024) void k_reduceS() {
    const int t = threadIdx.x, b = blockIdx.x;
    const int col = t & 63, sub = t >> 6;   // 16 subs x 16 partial-rows each
    const int c = b * 64 + col;
    float s = 0.f;
    #pragma unroll
    for (int j = 0; j < 16; ++j)
        s += g_partials[(size_t)(sub * 16 + j) * NCOLS + c];
    __shared__ float sh[16][65];
    sh[sub][col] = s;
    __syncthreads();
    if (t < 64) {                           // exactly one wave
        float tot = 0.f;
        #pragma unroll
        for (int i = 0; i < 16; ++i) tot += sh[i][t];
        g_S[c] = tot;
        float sq = tot * tot;
        #pragma unroll
        for (int off = 32; off; off >>= 1) sq += __shfl_xor(sq, off);
        if (t == 0) g_msq[b] = sq;
    }
}

// ---- K3: per-row |dot|/xnorm (2048 blocks x 256, one wave per row) ----
__global__ __launch_bounds__(256) void k_cos(const float* __restrict__ labels,
                                             const float* __restrict__ datas) {
    const int t = threadIdx.x, lane = t & 63, w = t >> 6;
    const int r = blockIdx.x * 4 + w;
    const float4* d4 = (const float4*)datas;
    const float4* s4 = (const float4*)g_S;
    const size_t base = (size_t)r * NC4;
    float dot = 0.f, sq = 0.f;
    float4 v[8];
    #pragma unroll
    for (int half = 0; half < 2; ++half) {
        #pragma unroll
        for (int k = 0; k < 8; ++k)
            v[k] = d4[base + lane + ((half * 8 + k) << 6)];
        #pragma unroll
        for (int k = 0; k < 8; ++k) {
            float4 sv = s4[lane + ((half * 8 + k) << 6)];
            dot += v[k].x * sv.x + v[k].y * sv.y + v[k].z * sv.z + v[k].w * sv.w;
            sq  += v[k].x * v[k].x + v[k].y * v[k].y + v[k].z * v[k].z + v[k].w * v[k].w;
        }
    }
    #pragma unroll
    for (int off = 32; off; off >>= 1) {
        dot += __shfl_xor(dot, off);
        sq  += __shfl_xor(sq, off);
    }
    __shared__ float shA[4], shB[4];
    if (lane == 0) {
        float a = fabsf(dot) / fmaxf(sqrtf(sq), EPS);  // |dot|/||x|| ; /||S|| later
        float l0 = labels[2 * r], l1 = labels[2 * r + 1];
        bool m0 = (l0 >= l1);
        shA[w] = m0 ? a : 0.f;
        shB[w] = m0 ? 0.f : a;
    }
    __syncthreads();
    if (t == 0) {
        g_A[blockIdx.x] = shA[0] + shA[1] + shA[2] + shA[3];
        g_B[blockIdx.x] = shB[0] + shB[1] + shB[2] + shB[3];
    }
}

// ---- K4: final scalar reduction -> 3 outputs (1 block x 1024) ----
__global__ __launch_bounds__(1024) void k_final(float* __restrict__ out) {
    const int t = threadIdx.x, lane = t & 63, w = t >> 6;
    float A = g_A[t] + g_A[t + 1024];
    float B = g_B[t] + g_B[t + 1024];
    float n0 = (t < 256) ? g_n0[t] : 0.f;
    float msq = (t < 64) ? g_msq[t] : 0.f;
    #pragma unroll
    for (int off = 32; off; off >>= 1) {
        A   += __shfl_xor(A, off);
        B   += __shfl_xor(B, off);
        n0  += __shfl_xor(n0, off);
        msq += __shfl_xor(msq, off);
    }
    __shared__ float sh[16][4];
    if (lane == 0) { sh[w][0] = A; sh[w][1] = B; sh[w][2] = n0; sh[w][3] = msq; }
    __syncthreads();
    if (t == 0) {
        float At = 0.f, Bt = 0.f, n0t = 0.f, mt = 0.f;
        #pragma unroll
        for (int i = 0; i < 16; ++i) {
            At += sh[i][0]; Bt += sh[i][1]; n0t += sh[i][2]; mt += sh[i][3];
        }
        float n1 = (float)NROWS - n0t;
        float n0d = fmaxf(n0t, 1.f), n1d = fmaxf(n1, 1.f);
        // n0d * max(||S||/n0d, eps) == max(||S||, n0d*eps)
        float D = fmaxf(sqrtf(mt), n0d * EPS);
        float simL = (n0t > 0.f) ? (n0t - At / D) / n0d : 0.f;
        float difL = (n0t > 0.f && n1 > 0.f) ? (Bt / D) / n1d : 0.f;
        out[0] = simL + difL;
        out[1] = simL;
        out[2] = difL;
    }
}

extern "C" void kernel_launch(void* const* d_in, const int* in_sizes, int n_in,
                              void* d_out, int out_size, void* d_ws, size_t ws_size,
                              hipStream_t stream) {
    const float* labels = (const float*)d_in[0];
    const float* datas  = (const float*)d_in[1];
    float* out = (float*)d_out;

    k_colsum<<<256, 1024, 0, stream>>>(labels, datas);
    k_reduceS<<<64, 1024, 0, stream>>>();
    k_cos<<<2048, 256, 0, stream>>>(labels, datas);
    k_final<<<1, 1024, 0, stream>>>(out);
}